// Round 1
// 1468.516 us; speedup vs baseline: 1.9372x; 1.9372x over previous
//
#include <hip/hip_runtime.h>

// Problem dims (fixed)
#define BB 4
#define SS 512      // decoder len
#define EE 1024     // encoder len
#define HH 1024     // hidden
#define VV 32000    // vocab

typedef __attribute__((ext_vector_type(8))) short bf16x8;
typedef __attribute__((ext_vector_type(4))) float f32x4;

// fp32 -> bf16 with round-to-nearest-even, result in low 16 bits
__device__ __forceinline__ unsigned f2bf(float x) {
    unsigned u = __float_as_uint(x);
    return (u + 0x7FFFu + ((u >> 16) & 1u)) >> 16;
}

// ---------------------------------------------------------------------------
// Embedding: x0[b*S+s, :] = tok_emb[tok[b,s], :] + pos_emb[s, :]
// ---------------------------------------------------------------------------
__global__ __launch_bounds__(256) void embed_kernel(
    const int* __restrict__ tok, const float* __restrict__ tokE,
    const float* __restrict__ posE, float* __restrict__ x0)
{
    int bs = blockIdx.x;                 // 0 .. B*S-1
    int s  = bs & (SS - 1);
    long t = (long)tok[bs];
    const float* te = tokE + t * HH;
    const float* pe = posE + (long)s * HH;
    float* xp = x0 + (long)bs * HH;
    for (int i = threadIdx.x; i < HH; i += 256)
        xp[i] = te[i] + pe[i];
}

// ---------------------------------------------------------------------------
// Tiled GEMM (NN): C[M,N] = A[M,K] @ B[K,N] (+ bias), batched via blockIdx.z.
// ---------------------------------------------------------------------------
__global__ __launch_bounds__(256) void gemm_nn_kernel(
    const float* __restrict__ A, const float* __restrict__ Bm,
    const float* __restrict__ bias, float* __restrict__ C,
    int M, int N, int K, long sA, long sB, long sC)
{
    A  += (long)blockIdx.z * sA;
    Bm += (long)blockIdx.z * sB;
    C  += (long)blockIdx.z * sC;

    __shared__ __align__(16) float As[16][68];   // [k][m]
    __shared__ __align__(16) float Bs[16][68];   // [k][n]

    const int tid = threadIdx.x;
    const int tx = tid & 15, ty = tid >> 4;
    const int row0 = blockIdx.y * 64, col0 = blockIdx.x * 64;

    float acc[4][4] = {};

    for (int k0 = 0; k0 < K; k0 += 16) {
        {
            int r  = tid >> 2;
            int kk = (tid & 3) << 2;
            const float* ap = A + (long)(row0 + r) * K + (k0 + kk);
            float a0 = ap[0], a1 = ap[1], a2 = ap[2], a3 = ap[3];
            As[kk + 0][r] = a0; As[kk + 1][r] = a1;
            As[kk + 2][r] = a2; As[kk + 3][r] = a3;
        }
        {
            int kr = tid >> 4;
            int c  = (tid & 15) << 2;
            const float* bp = Bm + (long)(k0 + kr) * N + (col0 + c);
            Bs[kr][c + 0] = bp[0]; Bs[kr][c + 1] = bp[1];
            Bs[kr][c + 2] = bp[2]; Bs[kr][c + 3] = bp[3];
        }
        __syncthreads();
#pragma unroll
        for (int k = 0; k < 16; ++k) {
            float4 av = *(const float4*)&As[k][ty << 2];
            float4 bv = *(const float4*)&Bs[k][tx << 2];
            acc[0][0] += av.x * bv.x; acc[0][1] += av.x * bv.y; acc[0][2] += av.x * bv.z; acc[0][3] += av.x * bv.w;
            acc[1][0] += av.y * bv.x; acc[1][1] += av.y * bv.y; acc[1][2] += av.y * bv.z; acc[1][3] += av.y * bv.w;
            acc[2][0] += av.z * bv.x; acc[2][1] += av.z * bv.y; acc[2][2] += av.z * bv.z; acc[2][3] += av.z * bv.w;
            acc[3][0] += av.w * bv.x; acc[3][1] += av.w * bv.y; acc[3][2] += av.w * bv.z; acc[3][3] += av.w * bv.w;
        }
        __syncthreads();
    }

    float bv4[4] = {0.f, 0.f, 0.f, 0.f};
    if (bias) {
        const float* bp = bias + col0 + (tx << 2);
        bv4[0] = bp[0]; bv4[1] = bp[1]; bv4[2] = bp[2]; bv4[3] = bp[3];
    }
#pragma unroll
    for (int i = 0; i < 4; ++i) {
        long row = row0 + (ty << 2) + i;
        float* cp = C + row * (long)N + col0 + (tx << 2);
#pragma unroll
        for (int j = 0; j < 4; ++j) cp[j] = acc[i][j] + bv4[j];
    }
}

// ---------------------------------------------------------------------------
// Tiled GEMM (NT): C[M,N] = A[M,K] @ B[N,K]^T  (scores = q @ k^T), fp32.
// ---------------------------------------------------------------------------
__global__ __launch_bounds__(256) void gemm_nt_kernel(
    const float* __restrict__ A, const float* __restrict__ Bm,
    float* __restrict__ C, int M, int N, int K, long sA, long sB, long sC)
{
    A  += (long)blockIdx.z * sA;
    Bm += (long)blockIdx.z * sB;
    C  += (long)blockIdx.z * sC;

    __shared__ __align__(16) float As[16][68];
    __shared__ __align__(16) float Bs[16][68];

    const int tid = threadIdx.x;
    const int tx = tid & 15, ty = tid >> 4;
    const int row0 = blockIdx.y * 64, col0 = blockIdx.x * 64;

    float acc[4][4] = {};

    for (int k0 = 0; k0 < K; k0 += 16) {
        {
            int r  = tid >> 2;
            int kk = (tid & 3) << 2;
            const float* ap = A + (long)(row0 + r) * K + (k0 + kk);
            As[kk + 0][r] = ap[0]; As[kk + 1][r] = ap[1];
            As[kk + 2][r] = ap[2]; As[kk + 3][r] = ap[3];
        }
        {
            int n  = tid >> 2;
            int kk = (tid & 3) << 2;
            const float* bp = Bm + (long)(col0 + n) * K + (k0 + kk);
            Bs[kk + 0][n] = bp[0]; Bs[kk + 1][n] = bp[1];
            Bs[kk + 2][n] = bp[2]; Bs[kk + 3][n] = bp[3];
        }
        __syncthreads();
#pragma unroll
        for (int k = 0; k < 16; ++k) {
            float4 av = *(const float4*)&As[k][ty << 2];
            float4 bv = *(const float4*)&Bs[k][tx << 2];
            acc[0][0] += av.x * bv.x; acc[0][1] += av.x * bv.y; acc[0][2] += av.x * bv.z; acc[0][3] += av.x * bv.w;
            acc[1][0] += av.y * bv.x; acc[1][1] += av.y * bv.y; acc[1][2] += av.y * bv.z; acc[1][3] += av.y * bv.w;
            acc[2][0] += av.z * bv.x; acc[2][1] += av.z * bv.y; acc[2][2] += av.z * bv.z; acc[2][3] += av.z * bv.w;
            acc[3][0] += av.w * bv.x; acc[3][1] += av.w * bv.y; acc[3][2] += av.w * bv.z; acc[3][3] += av.w * bv.w;
        }
        __syncthreads();
    }
#pragma unroll
    for (int i = 0; i < 4; ++i) {
        long row = row0 + (ty << 2) + i;
        float* cp = C + row * (long)N + col0 + (tx << 2);
#pragma unroll
        for (int j = 0; j < 4; ++j) cp[j] = acc[i][j];
    }
}

// ---------------------------------------------------------------------------
// Row softmax with scale + optional causal mask.
// ---------------------------------------------------------------------------
__global__ __launch_bounds__(256) void softmax_kernel(
    float* __restrict__ sc, int S, int rowlen, int causal, float scale)
{
    long rid = blockIdx.x;           // b*S + i
    int i = (int)(rid % S);
    int L = causal ? (i + 1) : rowlen;
    float* row = sc + rid * (long)rowlen;
    int tid = threadIdx.x;

    __shared__ float redA[4];
    __shared__ float redB[4];

    float m = -1e30f;
    for (int j = tid; j < L; j += 256) m = fmaxf(m, row[j] * scale);
#pragma unroll
    for (int off = 32; off > 0; off >>= 1) m = fmaxf(m, __shfl_down(m, off, 64));
    if ((tid & 63) == 0) redA[tid >> 6] = m;
    __syncthreads();
    m = fmaxf(fmaxf(redA[0], redA[1]), fmaxf(redA[2], redA[3]));

    float s = 0.f;
    for (int j = tid; j < L; j += 256) {
        float e = __expf(row[j] * scale - m);
        row[j] = e;
        s += e;
    }
#pragma unroll
    for (int off = 32; off > 0; off >>= 1) s += __shfl_down(s, off, 64);
    if ((tid & 63) == 0) redB[tid >> 6] = s;
    __syncthreads();
    s = redB[0] + redB[1] + redB[2] + redB[3];
    float inv = 1.f / s;

    for (int j = tid; j < L; j += 256) row[j] *= inv;
    for (int j = L + tid; j < rowlen; j += 256) row[j] = 0.f;   // masked tail -> 0
}

// ---------------------------------------------------------------------------
// fp32 -> bf16 (RNE), 8 elems/thread, vectorized.
// ---------------------------------------------------------------------------
__global__ __launch_bounds__(256) void f32_to_bf16_kernel(
    const float* __restrict__ in, unsigned* __restrict__ out, int n8)
{
    int i = blockIdx.x * 256 + threadIdx.x;
    if (i >= n8) return;
    const float4* ip = (const float4*)in + (long)i * 2;
    float4 a = ip[0], b = ip[1];
    uint4 o;
    o.x = f2bf(a.x) | (f2bf(a.y) << 16);
    o.y = f2bf(a.z) | (f2bf(a.w) << 16);
    o.z = f2bf(b.x) | (f2bf(b.y) << 16);
    o.w = f2bf(b.z) | (f2bf(b.w) << 16);
    ((uint4*)out)[i] = o;
}

// ---------------------------------------------------------------------------
// Logits GEMM via bf16 MFMA: C[2048,32000] = Ab(bf16)[2048,1024] @ Bw(fp32->bf16)
//                                            [1024,32000] + bias, fp32 out.
// 128x128 tile, BK=32, 4 waves (2x2 of 64x64), 16x16x32 MFMA.
//   A: staged with global_load_lds (width 16) into linear [128][32] bf16
//      (64B row stride -> 16B granules evenly spread mod 128B, conflict-free
//       ds_read_b128 fragments).
//   B: fp32 tile read coalesced (float4 x 4 rows), converted to bf16 in-reg,
//      written as ds_write_b64 into k-block-subtiled layout
//      Bs[kb][perm(n)][8], perm(n)=n^((n>>3)&7)  -> contiguous b128 fragment
//      reads, ~4-way (not 16-way) staging-write conflicts.
// ---------------------------------------------------------------------------
__global__ __launch_bounds__(256) void gemm_logits_kernel(
    const unsigned short* __restrict__ Ab,   // bf16 [2048][1024]
    const float* __restrict__ Bw,            // fp32 [1024][32000]
    const float* __restrict__ bias,          // [32000]
    float* __restrict__ C)                   // fp32 [2048][32000]
{
    __shared__ __align__(16) unsigned short As[128 * 32];    // 8 KB
    __shared__ __align__(16) unsigned short Bs[4 * 128 * 8]; // 8 KB

    const int tid  = threadIdx.x;
    const int lane = tid & 63;
    const int w    = tid >> 6;           // wave 0..3
    const int wr   = w >> 1, wc = w & 1; // 2x2 wave grid, each 64x64
    const int row0 = blockIdx.y * 128;
    const int col0 = blockIdx.x * 128;

    // B staging assignment: thread -> (n-quad, k-quad)
    const int nq  = tid & 31;   // 32 n-quads cover 128 cols
    const int q   = tid >> 5;   // 8 k-quads cover 32 k rows
    const int kbw = q >> 1, kq2 = q & 1;

    f32x4 acc[4][4];
#pragma unroll
    for (int mf = 0; mf < 4; ++mf)
#pragma unroll
        for (int nf = 0; nf < 4; ++nf)
            acc[mf][nf] = (f32x4){0.f, 0.f, 0.f, 0.f};

    for (int k0 = 0; k0 < HH; k0 += 32) {
        // ---- stage A: 2 x global_load_lds(16B) per thread, linear layout
#pragma unroll
        for (int r = 0; r < 2; ++r) {
            int G = r * 256 + tid;   // granule id: row = G>>2, k-oct = G&3
            const unsigned short* src =
                Ab + (long)(row0 + (G >> 2)) * HH + k0 + (G & 3) * 8;
            __builtin_amdgcn_global_load_lds(
                (const __attribute__((address_space(1))) unsigned int*)src,
                (__attribute__((address_space(3))) unsigned int*)
                    ((char*)As + r * 4096 + w * 1024),
                16, 0, 0);
        }
        // ---- stage B: 4 fp32 rows x 4 cols -> bf16, transposed subtile layout
        {
            const float* bp = Bw + (long)(k0 + q * 4) * VV + col0 + nq * 4;
            float4 r0 = *(const float4*)bp;
            float4 r1 = *(const float4*)(bp + VV);
            float4 r2 = *(const float4*)(bp + 2 * (long)VV);
            float4 r3 = *(const float4*)(bp + 3 * (long)VV);
#define PACK_STORE(i, c0, c1, c2, c3) {                                        \
            int n_  = nq * 4 + (i);                                            \
            int pn_ = n_ ^ ((n_ >> 3) & 7);                                    \
            *(uint2*)((char*)Bs + kbw * 2048 + pn_ * 16 + kq2 * 8) =           \
                make_uint2(f2bf(c0) | (f2bf(c1) << 16),                        \
                           f2bf(c2) | (f2bf(c3) << 16)); }
            PACK_STORE(0, r0.x, r1.x, r2.x, r3.x)
            PACK_STORE(1, r0.y, r1.y, r2.y, r3.y)
            PACK_STORE(2, r0.z, r1.z, r2.z, r3.z)
            PACK_STORE(3, r0.w, r1.w, r2.w, r3.w)
#undef PACK_STORE
        }
        __syncthreads();

        // ---- fragments + MFMA (16 per wave per K-step)
        bf16x8 af[4], bfr[4];
#pragma unroll
        for (int mf = 0; mf < 4; ++mf)
            af[mf] = *(const bf16x8*)((const char*)As +
                     (wr * 64 + mf * 16 + (lane & 15)) * 64 + (lane >> 4) * 16);
#pragma unroll
        for (int nf = 0; nf < 4; ++nf) {
            int n_  = wc * 64 + nf * 16 + (lane & 15);
            int pn_ = n_ ^ ((n_ >> 3) & 7);
            bfr[nf] = *(const bf16x8*)((const char*)Bs +
                      (lane >> 4) * 2048 + pn_ * 16);
        }
#pragma unroll
        for (int mf = 0; mf < 4; ++mf)
#pragma unroll
            for (int nf = 0; nf < 4; ++nf)
                acc[mf][nf] = __builtin_amdgcn_mfma_f32_16x16x32_bf16(
                    af[mf], bfr[nf], acc[mf][nf], 0, 0, 0);
        __syncthreads();
    }

    // ---- epilogue: C/D layout col=lane&15, row=(lane>>4)*4+r
    const int cbase = col0 + wc * 64 + (lane & 15);
    float bv[4];
#pragma unroll
    for (int nf = 0; nf < 4; ++nf) bv[nf] = bias[cbase + nf * 16];
#pragma unroll
    for (int mf = 0; mf < 4; ++mf) {
#pragma unroll
        for (int r = 0; r < 4; ++r) {
            long row = row0 + wr * 64 + mf * 16 + (lane >> 4) * 4 + r;
            float* cp = C + row * (long)VV + cbase;
#pragma unroll
            for (int nf = 0; nf < 4; ++nf) cp[nf * 16] = acc[mf][nf][r] + bv[nf];
        }
    }
}

// ---------------------------------------------------------------------------
extern "C" void kernel_launch(void* const* d_in, const int* in_sizes, int n_in,
                              void* d_out, int out_size, void* d_ws, size_t ws_size,
                              hipStream_t stream)
{
    const float* enc   = (const float*)d_in[0];   // [4,1024,1024]
    const int*   tok   = (const int*)  d_in[1];   // [4,512]
    const float* tokE  = (const float*)d_in[2];   // [32000,1024]
    const float* posE  = (const float*)d_in[3];   // [2048,1024]
    const float* Wq_s  = (const float*)d_in[4];
    const float* bq_s  = (const float*)d_in[5];
    const float* Wk_s  = (const float*)d_in[6];
    const float* bk_s  = (const float*)d_in[7];
    const float* Wv_s  = (const float*)d_in[8];
    const float* bv_s  = (const float*)d_in[9];
    const float* Wq_c  = (const float*)d_in[10];
    const float* bq_c  = (const float*)d_in[11];
    const float* Wk_c  = (const float*)d_in[12];
    const float* bk_c  = (const float*)d_in[13];
    const float* Wv_c  = (const float*)d_in[14];
    const float* bv_c  = (const float*)d_in[15];
    const float* Wout  = (const float*)d_in[16];  // [1024,32000]
    const float* bout  = (const float*)d_in[17];  // [32000]
    float* out = (float*)d_out;                   // [4,512,32000] fp32

    // Workspace layout (floats), lifetime-overlapped. 1M = 1,048,576.
    //   [ 0, 2M): x0, later x2
    //   [ 2, 4M): q (self), later qC, later x2b (bf16, 1M slots)
    //   [ 4, 6M): k (self), later x1
    //   [ 6, 8M): v (self)        }
    //   [ 8, 9M): scS             }-- kC overlays [6,10M) after step 5
    //   [ 6,10M): kC (cross K)
    //   [10,14M): vC (cross V)
    //   [14,16M): scC
    // Total 16M floats = 64 MB.
    float* ws = (float*)d_ws;
    const long M1 = 1048576;
    float* x0   = ws + 0 * M1;
    float* q    = ws + 2 * M1;
    float* kbuf = ws + 4 * M1;
    float* vbuf = ws + 6 * M1;
    float* scS  = ws + 8 * M1;
    float* kC   = ws + 6 * M1;   // overlays v,scS (dead after step 5)
    float* vC   = ws + 10 * M1;
    float* scC  = ws + 14 * M1;
    float* x1   = ws + 4 * M1;   // overlays k (dead after step 3)
    float* qC   = ws + 2 * M1;   // overlays q (dead after step 3)
    float* x2   = ws + 0 * M1;   // overlays x0 (dead after step 2)
    unsigned short* x2b = (unsigned short*)(ws + 2 * M1);  // bf16 x2 (qC dead)

    dim3 blk(256);
    const float scale = 0.03125f;  // 1/sqrt(1024)

    // 1) embedding
    embed_kernel<<<BB * SS, blk, 0, stream>>>(tok, tokE, posE, x0);

    // 2) self-attn projections q,k,v = x0 @ W + b   [2048,1024]
    dim3 gProj(HH / 64, (BB * SS) / 64, 1);
    gemm_nn_kernel<<<gProj, blk, 0, stream>>>(x0, Wq_s, bq_s, q,    BB*SS, HH, HH, 0, 0, 0);
    gemm_nn_kernel<<<gProj, blk, 0, stream>>>(x0, Wk_s, bk_s, kbuf, BB*SS, HH, HH, 0, 0, 0);
    gemm_nn_kernel<<<gProj, blk, 0, stream>>>(x0, Wv_s, bv_s, vbuf, BB*SS, HH, HH, 0, 0, 0);

    // 3) self scores [b,512,512] = q @ k^T
    dim3 gScS(SS / 64, SS / 64, BB);
    gemm_nt_kernel<<<gScS, blk, 0, stream>>>(q, kbuf, scS, SS, SS, HH,
                                             (long)SS * HH, (long)SS * HH, (long)SS * SS);
    // 4) causal softmax
    softmax_kernel<<<BB * SS, blk, 0, stream>>>(scS, SS, SS, 1, scale);

    // 5) x1 = P @ v   [b,512,1024], K=512
    dim3 gPV1(HH / 64, SS / 64, BB);
    gemm_nn_kernel<<<gPV1, blk, 0, stream>>>(scS, vbuf, nullptr, x1, SS, HH, SS,
                                             (long)SS * SS, (long)SS * HH, (long)SS * HH);

    // 6) cross q = x1 @ Wq_c + bq_c
    gemm_nn_kernel<<<gProj, blk, 0, stream>>>(x1, Wq_c, bq_c, qC, BB*SS, HH, HH, 0, 0, 0);

    // 7) cross k,v = enc @ W + b   (enc as [4096,1024])
    dim3 gEnc(HH / 64, (BB * EE) / 64, 1);
    gemm_nn_kernel<<<gEnc, blk, 0, stream>>>(enc, Wk_c, bk_c, kC, BB*EE, HH, HH, 0, 0, 0);
    gemm_nn_kernel<<<gEnc, blk, 0, stream>>>(enc, Wv_c, bv_c, vC, BB*EE, HH, HH, 0, 0, 0);

    // 8) cross scores [b,512,1024] = q_c @ k_c^T
    dim3 gScC(EE / 64, SS / 64, BB);
    gemm_nt_kernel<<<gScC, blk, 0, stream>>>(qC, kC, scC, SS, EE, HH,
                                             (long)SS * HH, (long)EE * HH, (long)SS * EE);
    // 9) softmax (no mask)
    softmax_kernel<<<BB * SS, blk, 0, stream>>>(scC, SS, EE, 0, scale);

    // 10) x2 = P @ v_c   [b,512,1024], K=1024
    dim3 gPV2(HH / 64, SS / 64, BB);
    gemm_nn_kernel<<<gPV2, blk, 0, stream>>>(scC, vC, nullptr, x2, SS, HH, EE,
                                             (long)SS * EE, (long)EE * HH, (long)SS * HH);

    // 11a) x2 -> bf16 (RNE). 2M elems, 8/thread -> 1024 blocks exactly.
    f32_to_bf16_kernel<<<1024, blk, 0, stream>>>(x2, (unsigned*)x2b,
                                                 (BB * SS * HH) / 8);

    // 11b) logits = x2b @ Wout + bout via bf16 MFMA -> fp32 out [2048,32000]
    dim3 gL(VV / 128, (BB * SS) / 128, 1);   // 250 x 16
    gemm_logits_kernel<<<gL, blk, 0, stream>>>(x2b, Wout, bout, out);
}

// Round 2
// 881.729 us; speedup vs baseline: 3.2265x; 1.6655x over previous
//
#include <hip/hip_runtime.h>

// Problem dims (fixed)
#define BB 4
#define SS 512      // decoder len
#define EE 1024     // encoder len
#define HH 1024     // hidden
#define VV 32000    // vocab

typedef __attribute__((ext_vector_type(8))) short bf16x8;
typedef __attribute__((ext_vector_type(4))) float f32x4;
typedef unsigned short u16;

// fp32 -> bf16 with round-to-nearest-even, result in low 16 bits
__device__ __forceinline__ unsigned f2bf(float x) {
    unsigned u = __float_as_uint(x);
    return (u + 0x7FFFu + ((u >> 16) & 1u)) >> 16;
}

// ---------------------------------------------------------------------------
// Embedding -> bf16: x0b[b*S+s, :] = bf16(tok_emb[tok[b,s], :] + pos_emb[s, :])
// ---------------------------------------------------------------------------
__global__ __launch_bounds__(256) void embed_bf16_kernel(
    const int* __restrict__ tok, const float* __restrict__ tokE,
    const float* __restrict__ posE, u16* __restrict__ x0b)
{
    int bs = blockIdx.x;                 // 0 .. B*S-1
    int s  = bs & (SS - 1);
    long t = (long)tok[bs];
    const float4* te = (const float4*)(tokE + t * HH);
    const float4* pe = (const float4*)(posE + (long)s * HH);
    uint2* xp = (uint2*)(x0b + (long)bs * HH);
    int i = threadIdx.x;                 // 1024/4 = 256 exactly
    float4 a = te[i], b = pe[i];
    xp[i] = make_uint2(f2bf(a.x + b.x) | (f2bf(a.y + b.y) << 16),
                       f2bf(a.z + b.z) | (f2bf(a.w + b.w) << 16));
}

// ---------------------------------------------------------------------------
// fp32 -> bf16 (RNE), 8 elems/thread, vectorized.  (used for enc)
// ---------------------------------------------------------------------------
__global__ __launch_bounds__(256) void f32_to_bf16_kernel(
    const float* __restrict__ in, unsigned* __restrict__ out, int n8)
{
    int i = blockIdx.x * 256 + threadIdx.x;
    if (i >= n8) return;
    const float4* ip = (const float4*)in + (long)i * 2;
    float4 a = ip[0], b = ip[1];
    uint4 o;
    o.x = f2bf(a.x) | (f2bf(a.y) << 16);
    o.y = f2bf(a.z) | (f2bf(a.w) << 16);
    o.z = f2bf(b.x) | (f2bf(b.y) << 16);
    o.w = f2bf(b.z) | (f2bf(b.w) << 16);
    ((uint4*)out)[i] = o;
}

// ---------------------------------------------------------------------------
// Transpose-convert all 6 [1024,1024] fp32 weights -> bf16 [N,K] slabs.
// blockIdx.z selects the weight; 64x64 tiles via LDS.
// ---------------------------------------------------------------------------
__global__ __launch_bounds__(256) void wcat_t_bf16_kernel(
    const float* W0, const float* W1, const float* W2,
    const float* W3, const float* W4, const float* W5,
    u16* __restrict__ Wt)
{
    const float* Ws[6] = {W0, W1, W2, W3, W4, W5};
    const float* W = Ws[blockIdx.z];                 // wave-uniform select
    u16* dst = Wt + (long)blockIdx.z * (HH * HH);

    __shared__ u16 T[64][72];                        // 72*2=144B rows (16B mult)
    int n0 = blockIdx.x * 64, k0 = blockIdx.y * 64;
    int tid = threadIdx.x;
    int tx = tid & 63, ty = tid >> 6;
#pragma unroll
    for (int r = 0; r < 16; ++r) {
        int k = (ty << 4) + r;
        T[tx][k] = (u16)f2bf(W[(long)(k0 + k) * HH + n0 + tx]);
    }
    __syncthreads();
    int n = tid >> 2, kq = (tid & 3) << 4;
    uint4 o0 = *(const uint4*)&T[n][kq];
    uint4 o1 = *(const uint4*)&T[n][kq + 8];
    u16* dp = dst + (long)(n0 + n) * HH + k0 + kq;
    *(uint4*)dp = o0;
    *(uint4*)(dp + 8) = o1;
}

// ---------------------------------------------------------------------------
// Concatenate the 6 bias vectors into one contiguous fp32 buffer.
// ---------------------------------------------------------------------------
__global__ __launch_bounds__(256) void bias_cat_kernel(
    const float* b0, const float* b1, const float* b2,
    const float* b3, const float* b4, const float* b5,
    float* __restrict__ dst)
{
    int i = blockIdx.x * 256 + threadIdx.x;          // grid 24 -> 6144
    const float* bs[6] = {b0, b1, b2, b3, b4, b5};
    dst[i] = bs[i >> 10][i & 1023];
}

// ---------------------------------------------------------------------------
// bf16 MFMA GEMM (NT): C[M,N] = A[M,K] @ Bt[N,K]^T (+bias), z-batched.
// 128x128 tile, BK=32, 4 waves (2x2 of 64x64), 16x16x32 MFMA.
// Both operands staged via global_load_lds (16B) into linear [128][32] bf16
// with XOR k-oct swizzle applied on the GLOBAL source (involution), matching
// swizzle on fragment reads -> 2-way (free) LDS bank access.
// outBf16: 1 -> bf16 output, 0 -> fp32 output.
// ---------------------------------------------------------------------------
__global__ __launch_bounds__(256) void gemm_bf16_nt_kernel(
    const u16* __restrict__ A, const u16* __restrict__ Bt,
    const float* __restrict__ bias, void* __restrict__ Cout,
    int M, int N, int K, long sA, long sB, long sC, long sBias, int outBf16)
{
    __shared__ __align__(16) u16 As[128 * 32];   // 8 KB
    __shared__ __align__(16) u16 Bs[128 * 32];   // 8 KB

    const u16* Az = A  + (long)blockIdx.z * sA;
    const u16* Bz = Bt + (long)blockIdx.z * sB;

    const int tid  = threadIdx.x;
    const int lane = tid & 63;
    const int w    = tid >> 6;
    const int wr   = w >> 1, wc = w & 1;
    const int row0 = blockIdx.y * 128, col0 = blockIdx.x * 128;

    const int lr = lane >> 2;                  // row-within-16-group for staging
    const int kl = (lane & 3) ^ (lr & 3);      // swizzled k-oct (global source)
    const int kq = (lane >> 4) ^ (lane & 3);   // swizzled k-oct (fragment read)

    f32x4 acc[4][4];
#pragma unroll
    for (int mf = 0; mf < 4; ++mf)
#pragma unroll
        for (int nf = 0; nf < 4; ++nf)
            acc[mf][nf] = (f32x4){0.f, 0.f, 0.f, 0.f};

    for (int k0 = 0; k0 < K; k0 += 32) {
#pragma unroll
        for (int r = 0; r < 2; ++r) {
            int rw = r * 64 + w * 16 + lr;
            __builtin_amdgcn_global_load_lds(
                (const __attribute__((address_space(1))) unsigned int*)
                    (Az + (long)(row0 + rw) * K + k0 + kl * 8),
                (__attribute__((address_space(3))) unsigned int*)
                    ((char*)As + r * 4096 + w * 1024), 16, 0, 0);
            __builtin_amdgcn_global_load_lds(
                (const __attribute__((address_space(1))) unsigned int*)
                    (Bz + (long)(col0 + rw) * K + k0 + kl * 8),
                (__attribute__((address_space(3))) unsigned int*)
                    ((char*)Bs + r * 4096 + w * 1024), 16, 0, 0);
        }
        __syncthreads();

        bf16x8 af[4], bfr[4];
#pragma unroll
        for (int mf = 0; mf < 4; ++mf)
            af[mf] = *(const bf16x8*)((const char*)As +
                     (wr * 64 + mf * 16 + (lane & 15)) * 64 + kq * 16);
#pragma unroll
        for (int nf = 0; nf < 4; ++nf)
            bfr[nf] = *(const bf16x8*)((const char*)Bs +
                      (wc * 64 + nf * 16 + (lane & 15)) * 64 + kq * 16);
#pragma unroll
        for (int mf = 0; mf < 4; ++mf)
#pragma unroll
            for (int nf = 0; nf < 4; ++nf)
                acc[mf][nf] = __builtin_amdgcn_mfma_f32_16x16x32_bf16(
                    af[mf], bfr[nf], acc[mf][nf], 0, 0, 0);
        __syncthreads();
    }

    const int cbase = col0 + wc * 64 + (lane & 15);
    float bv[4] = {0.f, 0.f, 0.f, 0.f};
    if (bias) {
        const float* bp = bias + (long)blockIdx.z * sBias;
#pragma unroll
        for (int nf = 0; nf < 4; ++nf) bv[nf] = bp[cbase + nf * 16];
    }
    if (outBf16) {
        u16* C = (u16*)Cout + (long)blockIdx.z * sC;
#pragma unroll
        for (int mf = 0; mf < 4; ++mf)
#pragma unroll
            for (int r = 0; r < 4; ++r) {
                long row = row0 + wr * 64 + mf * 16 + (lane >> 4) * 4 + r;
                u16* cp = C + row * (long)N + cbase;
#pragma unroll
                for (int nf = 0; nf < 4; ++nf)
                    cp[nf * 16] = (u16)f2bf(acc[mf][nf][r] + bv[nf]);
            }
    } else {
        float* C = (float*)Cout + (long)blockIdx.z * sC;
#pragma unroll
        for (int mf = 0; mf < 4; ++mf)
#pragma unroll
            for (int r = 0; r < 4; ++r) {
                long row = row0 + wr * 64 + mf * 16 + (lane >> 4) * 4 + r;
                float* cp = C + row * (long)N + cbase;
#pragma unroll
                for (int nf = 0; nf < 4; ++nf)
                    cp[nf * 16] = acc[mf][nf][r] + bv[nf];
            }
    }
}

// ---------------------------------------------------------------------------
// bf16 MFMA GEMM (NN): C[M,N] = A[M,K] @ B[K,N], bf16 out, z-batched. (P @ V)
// A staged as in NT (xor-swizzled global_load_lds); B bf16 [K,N] reg-staged,
// transposed in-register into the perm'd subtile layout Bs[kb][pn][8].
// ---------------------------------------------------------------------------
__global__ __launch_bounds__(256) void gemm_bf16_nn_kernel(
    const u16* __restrict__ A, const u16* __restrict__ B,
    u16* __restrict__ Cb, int M, int N, int K, long sA, long sB, long sC)
{
    __shared__ __align__(16) u16 As[128 * 32];    // 8 KB
    __shared__ __align__(16) u16 Bs[4 * 128 * 8]; // 8 KB

    const u16* Az = A + (long)blockIdx.z * sA;
    const u16* Bz = B + (long)blockIdx.z * sB;

    const int tid  = threadIdx.x;
    const int lane = tid & 63;
    const int w    = tid >> 6;
    const int wr   = w >> 1, wc = w & 1;
    const int row0 = blockIdx.y * 128, col0 = blockIdx.x * 128;

    const int lr = lane >> 2;
    const int kl = (lane & 3) ^ (lr & 3);
    const int kq = (lane >> 4) ^ (lane & 3);

    const int nq  = tid & 31;   // 4-col group
    const int q   = tid >> 5;   // k-quad
    const int kbw = q >> 1, kq2 = q & 1;

    f32x4 acc[4][4];
#pragma unroll
    for (int mf = 0; mf < 4; ++mf)
#pragma unroll
        for (int nf = 0; nf < 4; ++nf)
            acc[mf][nf] = (f32x4){0.f, 0.f, 0.f, 0.f};

    for (int k0 = 0; k0 < K; k0 += 32) {
#pragma unroll
        for (int r = 0; r < 2; ++r) {
            int rw = r * 64 + w * 16 + lr;
            __builtin_amdgcn_global_load_lds(
                (const __attribute__((address_space(1))) unsigned int*)
                    (Az + (long)(row0 + rw) * K + k0 + kl * 8),
                (__attribute__((address_space(3))) unsigned int*)
                    ((char*)As + r * 4096 + w * 1024), 16, 0, 0);
        }
        {
            const u16* bp = Bz + (long)(k0 + (q << 2)) * N + col0 + (nq << 2);
            ushort4 r0 = *(const ushort4*)bp;
            ushort4 r1 = *(const ushort4*)(bp + N);
            ushort4 r2 = *(const ushort4*)(bp + 2 * N);
            ushort4 r3 = *(const ushort4*)(bp + 3 * N);
#define PK(i, a, b, c, d) {                                                    \
            int n_  = (nq << 2) + (i);                                         \
            int pn_ = n_ ^ ((n_ >> 3) & 7);                                    \
            *(uint2*)((char*)Bs + kbw * 2048 + pn_ * 16 + kq2 * 8) =           \
                make_uint2((unsigned)(a) | ((unsigned)(b) << 16),              \
                           (unsigned)(c) | ((unsigned)(d) << 16)); }
            PK(0, r0.x, r1.x, r2.x, r3.x)
            PK(1, r0.y, r1.y, r2.y, r3.y)
            PK(2, r0.z, r1.z, r2.z, r3.z)
            PK(3, r0.w, r1.w, r2.w, r3.w)
#undef PK
        }
        __syncthreads();

        bf16x8 af[4], bfr[4];
#pragma unroll
        for (int mf = 0; mf < 4; ++mf)
            af[mf] = *(const bf16x8*)((const char*)As +
                     (wr * 64 + mf * 16 + (lane & 15)) * 64 + kq * 16);
#pragma unroll
        for (int nf = 0; nf < 4; ++nf) {
            int n_  = wc * 64 + nf * 16 + (lane & 15);
            int pn_ = n_ ^ ((n_ >> 3) & 7);
            bfr[nf] = *(const bf16x8*)((const char*)Bs +
                      (lane >> 4) * 2048 + pn_ * 16);
        }
#pragma unroll
        for (int mf = 0; mf < 4; ++mf)
#pragma unroll
            for (int nf = 0; nf < 4; ++nf)
                acc[mf][nf] = __builtin_amdgcn_mfma_f32_16x16x32_bf16(
                    af[mf], bfr[nf], acc[mf][nf], 0, 0, 0);
        __syncthreads();
    }

    const int cbase = col0 + wc * 64 + (lane & 15);
    u16* C = Cb + (long)blockIdx.z * sC;
#pragma unroll
    for (int mf = 0; mf < 4; ++mf)
#pragma unroll
        for (int r = 0; r < 4; ++r) {
            long row = row0 + wr * 64 + mf * 16 + (lane >> 4) * 4 + r;
            u16* cp = C + row * (long)N + cbase;
#pragma unroll
            for (int nf = 0; nf < 4; ++nf)
                cp[nf * 16] = (u16)f2bf(acc[mf][nf][r]);
        }
}

// ---------------------------------------------------------------------------
// Row softmax (fp32 scores in) -> bf16 P out, scale + optional causal mask.
// Row held in registers (<=4 elems/thread), single global read pass.
// ---------------------------------------------------------------------------
__global__ __launch_bounds__(256) void softmax_bf16_kernel(
    const float* __restrict__ sc, u16* __restrict__ P,
    int rowlen, int causal, float scale)
{
    long rid = blockIdx.x;           // b*S + i
    int i = (int)(rid & (SS - 1));
    int L = causal ? (i + 1) : rowlen;
    const float* row = sc + rid * (long)rowlen;
    u16* prow = P + rid * (long)rowlen;
    int tid = threadIdx.x;

    __shared__ float redA[4];
    __shared__ float redB[4];

    float v[4];
    float m = -1e30f;
#pragma unroll 4
    for (int p = 0; p < 4; ++p) {
        int j = tid + (p << 8);
        v[p] = (j < L) ? row[j] * scale : -1e30f;
        m = fmaxf(m, v[p]);
    }
#pragma unroll
    for (int off = 32; off > 0; off >>= 1) m = fmaxf(m, __shfl_xor(m, off, 64));
    if ((tid & 63) == 0) redA[tid >> 6] = m;
    __syncthreads();
    m = fmaxf(fmaxf(redA[0], redA[1]), fmaxf(redA[2], redA[3]));

    float s = 0.f;
#pragma unroll 4
    for (int p = 0; p < 4; ++p) {
        int j = tid + (p << 8);
        v[p] = (j < L) ? __expf(v[p] - m) : 0.f;
        s += v[p];
    }
#pragma unroll
    for (int off = 32; off > 0; off >>= 1) s += __shfl_xor(s, off, 64);
    if ((tid & 63) == 0) redB[tid >> 6] = s;
    __syncthreads();
    s = redB[0] + redB[1] + redB[2] + redB[3];
    float inv = 1.f / s;

#pragma unroll 4
    for (int p = 0; p < 4; ++p) {
        int j = tid + (p << 8);
        if (j < rowlen) prow[j] = (u16)f2bf(v[p] * inv);   // tail -> 0
    }
}

// ---------------------------------------------------------------------------
// Logits GEMM: C[2048,32000] = x2b(bf16) @ Wout(fp32->bf16) + bout, fp32 out.
// Same structure as NT kernel but B is fp32 [K,N] converted in-register.
// 1-D grid of 4000 with bijective XCD-chunked swizzle: 16 row-blocks of one
// Wout col-panel land consecutively on one XCD -> panel read ~once per XCD.
// ---------------------------------------------------------------------------
__global__ __launch_bounds__(256) void gemm_logits_kernel(
    const u16* __restrict__ Ab,              // bf16 [2048][1024]
    const float* __restrict__ Bw,            // fp32 [1024][32000]
    const float* __restrict__ bias,          // [32000]
    float* __restrict__ C)                   // fp32 [2048][32000]
{
    __shared__ __align__(16) u16 As[128 * 32];    // 8 KB
    __shared__ __align__(16) u16 Bs[4 * 128 * 8]; // 8 KB

    const int bid = blockIdx.x;                  // 0..3999 (= 8 * 500)
    const int g   = (bid & 7) * 500 + (bid >> 3);
    const int row0 = (g & 15) * 128;
    const int col0 = (g >> 4) * 128;

    const int tid  = threadIdx.x;
    const int lane = tid & 63;
    const int w    = tid >> 6;
    const int wr   = w >> 1, wc = w & 1;

    const int lr = lane >> 2;
    const int kl = (lane & 3) ^ (lr & 3);
    const int kq = (lane >> 4) ^ (lane & 3);

    const int nq  = tid & 31;
    const int q   = tid >> 5;
    const int kbw = q >> 1, kq2 = q & 1;

    f32x4 acc[4][4];
#pragma unroll
    for (int mf = 0; mf < 4; ++mf)
#pragma unroll
        for (int nf = 0; nf < 4; ++nf)
            acc[mf][nf] = (f32x4){0.f, 0.f, 0.f, 0.f};

    for (int k0 = 0; k0 < HH; k0 += 32) {
#pragma unroll
        for (int r = 0; r < 2; ++r) {
            int rw = r * 64 + w * 16 + lr;
            __builtin_amdgcn_global_load_lds(
                (const __attribute__((address_space(1))) unsigned int*)
                    (Ab + (long)(row0 + rw) * HH + k0 + kl * 8),
                (__attribute__((address_space(3))) unsigned int*)
                    ((char*)As + r * 4096 + w * 1024), 16, 0, 0);
        }
        {
            const float* bp = Bw + (long)(k0 + q * 4) * VV + col0 + nq * 4;
            float4 r0 = *(const float4*)bp;
            float4 r1 = *(const float4*)(bp + VV);
            float4 r2 = *(const float4*)(bp + 2 * (long)VV);
            float4 r3 = *(const float4*)(bp + 3 * (long)VV);
#define PACK_STORE(i, c0, c1, c2, c3) {                                        \
            int n_  = nq * 4 + (i);                                            \
            int pn_ = n_ ^ ((n_ >> 3) & 7);                                    \
            *(uint2*)((char*)Bs + kbw * 2048 + pn_ * 16 + kq2 * 8) =           \
                make_uint2(f2bf(c0) | (f2bf(c1) << 16),                        \
                           f2bf(c2) | (f2bf(c3) << 16)); }
            PACK_STORE(0, r0.x, r1.x, r2.x, r3.x)
            PACK_STORE(1, r0.y, r1.y, r2.y, r3.y)
            PACK_STORE(2, r0.z, r1.z, r2.z, r3.z)
            PACK_STORE(3, r0.w, r1.w, r2.w, r3.w)
#undef PACK_STORE
        }
        __syncthreads();

        bf16x8 af[4], bfr[4];
#pragma unroll
        for (int mf = 0; mf < 4; ++mf)
            af[mf] = *(const bf16x8*)((const char*)As +
                     (wr * 64 + mf * 16 + (lane & 15)) * 64 + kq * 16);
#pragma unroll
        for (int nf = 0; nf < 4; ++nf) {
            int n_  = wc * 64 + nf * 16 + (lane & 15);
            int pn_ = n_ ^ ((n_ >> 3) & 7);
            bfr[nf] = *(const bf16x8*)((const char*)Bs +
                      (lane >> 4) * 2048 + pn_ * 16);
        }
#pragma unroll
        for (int mf = 0; mf < 4; ++mf)
#pragma unroll
            for (int nf = 0; nf < 4; ++nf)
                acc[mf][nf] = __builtin_amdgcn_mfma_f32_16x16x32_bf16(
                    af[mf], bfr[nf], acc[mf][nf], 0, 0, 0);
        __syncthreads();
    }

    const int cbase = col0 + wc * 64 + (lane & 15);
    float bv[4];
#pragma unroll
    for (int nf = 0; nf < 4; ++nf) bv[nf] = bias[cbase + nf * 16];
#pragma unroll
    for (int mf = 0; mf < 4; ++mf) {
#pragma unroll
        for (int r = 0; r < 4; ++r) {
            long row = row0 + wr * 64 + mf * 16 + (lane >> 4) * 4 + r;
            float* cp = C + row * (long)VV + cbase;
#pragma unroll
            for (int nf = 0; nf < 4; ++nf) cp[nf * 16] = acc[mf][nf][r] + bv[nf];
        }
    }
}

// ---------------------------------------------------------------------------
extern "C" void kernel_launch(void* const* d_in, const int* in_sizes, int n_in,
                              void* d_out, int out_size, void* d_ws, size_t ws_size,
                              hipStream_t stream)
{
    const float* enc   = (const float*)d_in[0];   // [4,1024,1024]
    const int*   tok   = (const int*)  d_in[1];   // [4,512]
    const float* tokE  = (const float*)d_in[2];   // [32000,1024]
    const float* posE  = (const float*)d_in[3];   // [2048,1024]
    const float* Wq_s  = (const float*)d_in[4];
    const float* bq_s  = (const float*)d_in[5];
    const float* Wk_s  = (const float*)d_in[6];
    const float* bk_s  = (const float*)d_in[7];
    const float* Wv_s  = (const float*)d_in[8];
    const float* bv_s  = (const float*)d_in[9];
    const float* Wq_c  = (const float*)d_in[10];
    const float* bq_c  = (const float*)d_in[11];
    const float* Wk_c  = (const float*)d_in[12];
    const float* bk_c  = (const float*)d_in[13];
    const float* Wv_c  = (const float*)d_in[14];
    const float* bv_c  = (const float*)d_in[15];
    const float* Wout  = (const float*)d_in[16];  // [1024,32000]
    const float* bout  = (const float*)d_in[17];  // [32000]
    float* out = (float*)d_out;                   // [4,512,32000] fp32

    // Workspace layout (byte offsets, lifetime-overlapped). Total 55 MB.
    //   [ 0,12): Wt slabs (q_s,k_s,v_s,q_c,k_c,v_c), bf16 [N,K], 2 MB each
    //   [12,  ): biasbuf 24 KB (same slot order)
    //   [13,21): encb (bf16)          -> later scC (fp32)
    //   [21,25): qb   | [25,29): kb   -> later kCb (bf16, 8 MB)
    //   [29,33): vb   | [33,37): scS  -> later vCb (bf16, 8 MB)
    //   [37,39): Ps (bf16)
    //   [39,43): x1b                  -> later x2b
    //   [43,47): qCb
    //   [47,51): x0b
    //   [51,55): Pc (bf16)
    char* wsb = (char*)d_ws;
    const long MB = 1 << 20;
    u16*   wt      = (u16*)(wsb + 0);
    float* biasbuf = (float*)(wsb + 12 * MB);
    u16*   encb    = (u16*)(wsb + 13 * MB);
    float* scC     = (float*)(wsb + 13 * MB);
    u16*   qb      = (u16*)(wsb + 21 * MB);
    u16*   kb      = (u16*)(wsb + 25 * MB);
    u16*   vb      = (u16*)(wsb + 29 * MB);
    float* scS     = (float*)(wsb + 33 * MB);
    u16*   kCb     = (u16*)(wsb + 21 * MB);
    u16*   vCb     = (u16*)(wsb + 29 * MB);
    u16*   Ps      = (u16*)(wsb + 37 * MB);
    u16*   x1b     = (u16*)(wsb + 39 * MB);
    u16*   x2b     = (u16*)(wsb + 39 * MB);
    u16*   qCb     = (u16*)(wsb + 43 * MB);
    u16*   x0b     = (u16*)(wsb + 47 * MB);
    u16*   Pc      = (u16*)(wsb + 51 * MB);

    dim3 blk(256);
    const float scale = 0.03125f;  // 1/sqrt(1024)
    const long M1s = 1048576;      // shorts per weight slab

    // 0) conversions
    wcat_t_bf16_kernel<<<dim3(16, 16, 6), blk, 0, stream>>>(
        Wq_s, Wk_s, Wv_s, Wq_c, Wk_c, Wv_c, wt);
    bias_cat_kernel<<<24, blk, 0, stream>>>(bq_s, bk_s, bv_s, bq_c, bk_c, bv_c,
                                            biasbuf);
    f32_to_bf16_kernel<<<2048, blk, 0, stream>>>(enc, (unsigned*)encb,
                                                 (BB * EE * HH) / 8);
    embed_bf16_kernel<<<BB * SS, blk, 0, stream>>>(tok, tokE, posE, x0b);

    // 1) self q,k,v fused (z picks weight/bias/output)
    gemm_bf16_nt_kernel<<<dim3(8, 16, 3), blk, 0, stream>>>(
        x0b, wt, biasbuf, qb, BB * SS, HH, HH,
        0L, M1s, (long)BB * SS * HH, (long)HH, 1);

    // 2) self scores = q @ k^T (fp32 out)
    gemm_bf16_nt_kernel<<<dim3(4, 4, 4), blk, 0, stream>>>(
        qb, kb, nullptr, scS, SS, SS, HH,
        (long)SS * HH, (long)SS * HH, (long)SS * SS, 0L, 0);

    // 3) causal softmax -> bf16 P
    softmax_bf16_kernel<<<BB * SS, blk, 0, stream>>>(scS, Ps, SS, 1, scale);

    // 4) x1 = P @ v (bf16)
    gemm_bf16_nn_kernel<<<dim3(8, 4, 4), blk, 0, stream>>>(
        Ps, vb, x1b, SS, HH, SS,
        (long)SS * SS, (long)SS * HH, (long)SS * HH);

    // 5) cross q = x1 @ Wq_c + b
    gemm_bf16_nt_kernel<<<dim3(8, 16, 1), blk, 0, stream>>>(
        x1b, wt + 3 * M1s, biasbuf + 3 * 1024, qCb, BB * SS, HH, HH,
        0L, 0L, 0L, 0L, 1);

    // 6) cross k,v fused from enc
    gemm_bf16_nt_kernel<<<dim3(8, 32, 2), blk, 0, stream>>>(
        encb, wt + 4 * M1s, biasbuf + 4 * 1024, kCb, BB * EE, HH, HH,
        0L, M1s, (long)BB * EE * HH, (long)HH, 1);

    // 7) cross scores = qC @ kC^T (fp32 out)
    gemm_bf16_nt_kernel<<<dim3(8, 4, 4), blk, 0, stream>>>(
        qCb, kCb, nullptr, scC, SS, EE, HH,
        (long)SS * HH, (long)EE * HH, (long)SS * EE, 0L, 0);

    // 8) softmax (no mask) -> bf16 P
    softmax_bf16_kernel<<<BB * SS, blk, 0, stream>>>(scC, Pc, EE, 0, scale);

    // 9) x2 = P @ vC (bf16)
    gemm_bf16_nn_kernel<<<dim3(8, 4, 4), blk, 0, stream>>>(
        Pc, vCb, x2b, SS, HH, EE,
        (long)SS * EE, (long)EE * HH, (long)SS * HH);

    // 10) logits = x2b @ Wout + bout (XCD-swizzled 1-D grid, 4000 = 8*500)
    gemm_logits_kernel<<<4000, blk, 0, stream>>>(x2b, Wout, bout, out);
}